// Round 1
// baseline (333.591 us; speedup 1.0000x reference)
//
#include <hip/hip_runtime.h>
#include <math.h>

#define HDIM 4096
#define ODIM 50257
#define G3H  12288   // 3*HDIM

// ---------- helpers ----------

__device__ __forceinline__ float wave_reduce_sum(float v) {
#pragma unroll
    for (int off = 32; off > 0; off >>= 1) v += __shfl_down(v, off, 64);
    return v;  // valid on lane 0
}

// dot of a 4096-long row with a 4096-long vector, one wave (64 lanes)
__device__ __forceinline__ float dot4096(const float* __restrict__ Wrow,
                                         const float* __restrict__ v) {
    const float4* w4 = reinterpret_cast<const float4*>(Wrow);
    const float4* v4 = reinterpret_cast<const float4*>(v);
    const int lane = threadIdx.x & 63;
    float acc = 0.f;
#pragma unroll
    for (int t = 0; t < 16; ++t) {          // 16 * 64 lanes * 4 floats = 4096
        float4 a = w4[t * 64 + lane];
        float4 b = v4[t * 64 + lane];
        acc = fmaf(a.x, b.x, acc);
        acc = fmaf(a.y, b.y, acc);
        acc = fmaf(a.z, b.z, acc);
        acc = fmaf(a.w, b.w, acc);
    }
    return wave_reduce_sum(acc);
}

// monotone float<->uint mapping so atomicMax(uint) orders like float
__device__ __forceinline__ unsigned flipf(float f) {
    unsigned u = __float_as_uint(f);
    return (u & 0x80000000u) ? ~u : (u | 0x80000000u);
}
__device__ __forceinline__ float unflipf(unsigned u) {
    u = (u & 0x80000000u) ? (u ^ 0x80000000u) : ~u;
    return __uint_as_float(u);
}

// ---------- kernels ----------

// Two independent 12288x4096 GEMVs (gi = W_ih * x + b_ih ; gh = W_hh * h + b_hh).
// One wave per row; 4 waves/block; blocks are homogeneous (12288 % 4 == 0).
__global__ __launch_bounds__(256) void gemv_dual(
    const float* __restrict__ Wa, const float* __restrict__ va,
    const float* __restrict__ ba, float* __restrict__ oa,
    const float* __restrict__ Wb, const float* __restrict__ vb,
    const float* __restrict__ bb, float* __restrict__ ob) {
    int gw = (blockIdx.x * 256 + threadIdx.x) >> 6;  // global wave id
    const float* W; const float* v; const float* bs; float* o; int row;
    if (gw < G3H) { W = Wa; v = va; bs = ba; o = oa; row = gw; }
    else          { W = Wb; v = vb; bs = bb; o = ob; row = gw - G3H; }
    float d = dot4096(&W[(size_t)row * HDIM], v);
    if ((threadIdx.x & 63) == 0) o[row] = d + bs[row];
}

// GRU gate math for one step: h = (1-z)*n + z*hprev. Biases already in gi/gh.
// If act != nullptr also emits relu(h) and resets the softmax-max atomic slot.
__global__ void gru_gate(const float* __restrict__ gi, const float* __restrict__ gh,
                         const float* __restrict__ hprev, float* __restrict__ hout,
                         float* __restrict__ act, unsigned* __restrict__ maxbits) {
    int j = blockIdx.x * blockDim.x + threadIdx.x;
    if (j < HDIM) {
        float r = 1.f / (1.f + expf(-(gi[j] + gh[j])));
        float z = 1.f / (1.f + expf(-(gi[HDIM + j] + gh[HDIM + j])));
        float n = tanhf(gi[2 * HDIM + j] + r * gh[2 * HDIM + j]);
        float h = (1.f - z) * n + z * hprev[j];
        hout[j] = h;
        if (act) act[j] = fmaxf(h, 0.f);
    }
    if (act && blockIdx.x == 0 && threadIdx.x == 0) *maxbits = 0u;
}

// Logits GEMV: 50257 x 4096, one wave per row, 4 rows/block.
// Writes logits into d_out[0..ODIM) and atomicMax's the block max (flipped).
__global__ __launch_bounds__(256) void gemv_logits(
    const float* __restrict__ W, const float* __restrict__ v,
    const float* __restrict__ bias, float* __restrict__ out,
    unsigned* __restrict__ maxbits) {
    int wid = threadIdx.x >> 6;
    int row = blockIdx.x * 4 + wid;
    __shared__ float smax[4];
    float val = -INFINITY;
    if (row < ODIM) {
        float d = dot4096(&W[(size_t)row * HDIM], v);
        if ((threadIdx.x & 63) == 0) {
            val = d + bias[row];
            out[row] = val;
        }
    }
    if ((threadIdx.x & 63) == 0) smax[wid] = val;
    __syncthreads();
    if (threadIdx.x == 0) {
        float m = fmaxf(fmaxf(smax[0], smax[1]), fmaxf(smax[2], smax[3]));
        atomicMax(maxbits, flipf(m));
    }
}

// Per-block partial sums of exp(logit - max).
__global__ void sumexp_partial(const float* __restrict__ logits,
                               const unsigned* __restrict__ maxbits,
                               float* __restrict__ partial) {
    float m = unflipf(*maxbits);
    float s = 0.f;
    for (int i = blockIdx.x * blockDim.x + threadIdx.x; i < ODIM;
         i += gridDim.x * blockDim.x)
        s += expf(logits[i] - m);
    s = wave_reduce_sum(s);
    __shared__ float sm[4];
    int wid = threadIdx.x >> 6;
    if ((threadIdx.x & 63) == 0) sm[wid] = s;
    __syncthreads();
    if (threadIdx.x == 0) partial[blockIdx.x] = sm[0] + sm[1] + sm[2] + sm[3];
}

// Single wave: total sum + logC = max + log(sum)
__global__ void finalize_lse(const float* __restrict__ partial,
                             const unsigned* __restrict__ maxbits,
                             float* __restrict__ logC, int nb) {
    float s = (threadIdx.x < nb) ? partial[threadIdx.x] : 0.f;
    s = wave_reduce_sum(s);
    if (threadIdx.x == 0) *logC = unflipf(*maxbits) + logf(s);
}

// out[i] = logits[i] - logC
__global__ void logsm_final(float* __restrict__ out, const float* __restrict__ logC) {
    int i = blockIdx.x * blockDim.x + threadIdx.x;
    if (i < ODIM) out[i] -= *logC;
}

// ---------- launch ----------

extern "C" void kernel_launch(void* const* d_in, const int* in_sizes, int n_in,
                              void* d_out, int out_size, void* d_ws, size_t ws_size,
                              hipStream_t stream) {
    const float* x     = (const float*)d_in[0];   // [1,1,4096]
    const float* h0    = (const float*)d_in[1];   // [1,1,4096]
    const float* w_ih1 = (const float*)d_in[2];   // [12288,4096]
    const float* w_hh1 = (const float*)d_in[3];
    const float* b_ih1 = (const float*)d_in[4];
    const float* b_hh1 = (const float*)d_in[5];
    const float* w_ih2 = (const float*)d_in[6];
    const float* w_hh2 = (const float*)d_in[7];
    const float* b_ih2 = (const float*)d_in[8];
    const float* b_hh2 = (const float*)d_in[9];
    const float* w_out = (const float*)d_in[10];  // [50257,4096]
    const float* b_out = (const float*)d_in[11];

    float* out    = (float*)d_out;        // logits / log_softmax [50257]
    float* h2_out = out + ODIM;           // h2 [4096]

    float* ws      = (float*)d_ws;
    float* gi1     = ws;                  // 12288
    float* gh1     = ws + 12288;          // 12288
    float* gi2     = ws + 24576;          // 12288
    float* gh2     = ws + 36864;          // 12288
    float* h1      = ws + 49152;          // 4096
    float* act     = ws + 53248;          // 4096 (relu(h2))
    float* partial = ws + 57344;          // 64
    unsigned* maxbits = (unsigned*)(ws + 57408);
    float* logC    = ws + 57409;

    // Layer 1: gi1 = w_ih1*x + b_ih1 ; gh1 = w_hh1*h0 + b_hh1
    gemv_dual<<<2 * G3H / 4, 256, 0, stream>>>(w_ih1, x, b_ih1, gi1,
                                               w_hh1, h0, b_hh1, gh1);
    gru_gate<<<HDIM / 256, 256, 0, stream>>>(gi1, gh1, h0, h1, nullptr, nullptr);

    // Layer 2 (x2 = h2prev = h1)
    gemv_dual<<<2 * G3H / 4, 256, 0, stream>>>(w_ih2, h1, b_ih2, gi2,
                                               w_hh2, h1, b_hh2, gh2);
    gru_gate<<<HDIM / 256, 256, 0, stream>>>(gi2, gh2, h1, h2_out, act, maxbits);

    // Output projection + log_softmax
    gemv_logits<<<(ODIM + 3) / 4, 256, 0, stream>>>(w_out, act, b_out, out, maxbits);
    sumexp_partial<<<64, 256, 0, stream>>>(out, maxbits, partial);
    finalize_lse<<<1, 64, 0, stream>>>(partial, maxbits, logC, 64);
    logsm_final<<<(ODIM + 255) / 256, 256, 0, stream>>>(out, logC);
}

// Round 3
// 265.912 us; speedup vs baseline: 1.2545x; 1.2545x over previous
//
#include <hip/hip_runtime.h>
#include <math.h>

#define HDIM 4096
#define ODIM 50257
#define G3H  12288        // 3*HDIM
#define NBLK 2048         // blocks for the big GEMVs
#define NTHR 256

typedef float f32x4 __attribute__((ext_vector_type(4)));

// ---------- helpers ----------

__device__ __forceinline__ float wave_reduce_sum(float v) {
#pragma unroll
    for (int off = 32; off > 0; off >>= 1) v += __shfl_down(v, off, 64);
    return v;  // valid on lane 0
}

// dot of one 4096-long W row (global, nontemporal) with v staged in LDS
__device__ __forceinline__ float dot_row(const float* __restrict__ Wrow,
                                         const f32x4* __restrict__ vs,
                                         int lane) {
    const f32x4* w4 = reinterpret_cast<const f32x4*>(Wrow);
    float acc0 = 0.f, acc1 = 0.f;
#pragma unroll
    for (int t = 0; t < 16; t += 2) {
        f32x4 a0 = __builtin_nontemporal_load(&w4[t * 64 + lane]);
        f32x4 b0 = vs[t * 64 + lane];
        f32x4 a1 = __builtin_nontemporal_load(&w4[(t + 1) * 64 + lane]);
        f32x4 b1 = vs[(t + 1) * 64 + lane];
        acc0 = fmaf(a0.x, b0.x, acc0);
        acc0 = fmaf(a0.y, b0.y, acc0);
        acc0 = fmaf(a0.z, b0.z, acc0);
        acc0 = fmaf(a0.w, b0.w, acc0);
        acc1 = fmaf(a1.x, b1.x, acc1);
        acc1 = fmaf(a1.y, b1.y, acc1);
        acc1 = fmaf(a1.z, b1.z, acc1);
        acc1 = fmaf(a1.w, b1.w, acc1);
    }
    return wave_reduce_sum(acc0 + acc1);
}

// ---------- kernels ----------

// Two independent 12288x4096 GEMVs. Blocks [0,1024) do A, [1024,2048) do B.
// Each block stages its v into LDS and owns 12 contiguous rows (3 per wave).
__global__ __launch_bounds__(NTHR) void gemv_dual(
    const float* __restrict__ Wa, const float* __restrict__ va,
    const float* __restrict__ ba, float* __restrict__ oa,
    const float* __restrict__ Wb, const float* __restrict__ vb,
    const float* __restrict__ bb, float* __restrict__ ob) {
    __shared__ f32x4 vs[HDIM / 4];   // 16 KB
    const bool isB = blockIdx.x >= (NBLK / 2);
    const float* W  = isB ? Wb : Wa;
    const float* v  = isB ? vb : va;
    const float* bs = isB ? bb : ba;
    float*       o  = isB ? ob : oa;
    const int blk = isB ? (int)blockIdx.x - NBLK / 2 : (int)blockIdx.x;

    const f32x4* v4 = reinterpret_cast<const f32x4*>(v);
#pragma unroll
    for (int i = 0; i < 4; ++i)
        vs[i * NTHR + threadIdx.x] = v4[i * NTHR + threadIdx.x];
    __syncthreads();

    const int wid = threadIdx.x >> 6, lane = threadIdx.x & 63;
    const int row0 = blk * 12 + wid * 3;
#pragma unroll
    for (int r = 0; r < 3; ++r) {
        int row = row0 + r;
        float d = dot_row(&W[(size_t)row * HDIM], vs, lane);
        if (lane == 0) o[row] = d + bs[row];
    }
}

// GRU gate math: h = (1-z)*n + z*hprev. If act!=nullptr also emits relu(h).
__global__ void gru_gate(const float* __restrict__ gi, const float* __restrict__ gh,
                         const float* __restrict__ hprev, float* __restrict__ hout,
                         float* __restrict__ act) {
    int j = blockIdx.x * blockDim.x + threadIdx.x;
    if (j < HDIM) {
        float r = 1.f / (1.f + expf(-(gi[j] + gh[j])));
        float z = 1.f / (1.f + expf(-(gi[HDIM + j] + gh[HDIM + j])));
        float n = tanhf(gi[2 * HDIM + j] + r * gh[2 * HDIM + j]);
        float h = (1.f - z) * n + z * hprev[j];
        hout[j] = h;
        if (act) act[j] = fmaxf(h, 0.f);
    }
}

// Logits GEMV fused with per-block online log-sum-exp.
// Block b owns rows [b*24 + min(b,1105), +24 or 25); waves sub-split that.
__global__ __launch_bounds__(NTHR) void gemv_logits_lse(
    const float* __restrict__ W, const float* __restrict__ v,
    const float* __restrict__ bias, float* __restrict__ out,
    float2* __restrict__ pairs) {
    __shared__ f32x4 vs[HDIM / 4];   // 16 KB
    __shared__ float smx[4], ssm[4];

    const f32x4* v4 = reinterpret_cast<const f32x4*>(v);
#pragma unroll
    for (int i = 0; i < 4; ++i)
        vs[i * NTHR + threadIdx.x] = v4[i * NTHR + threadIdx.x];
    __syncthreads();

    const int b = blockIdx.x;
    const int start = b * 24 + min(b, 1105);
    const int cnt   = 24 + (b < 1105 ? 1 : 0);
    const int wid = threadIdx.x >> 6, lane = threadIdx.x & 63;
    const int wq = cnt >> 2, wr = cnt & 3;
    const int woff = wid * wq + min(wid, wr);
    const int wcnt = wq + (wid < wr ? 1 : 0);

    float m = -INFINITY, s = 0.f;
    for (int r = 0; r < wcnt; ++r) {
        int row = start + woff + r;
        float d = dot_row(&W[(size_t)row * HDIM], vs, lane);
        if (lane == 0) {
            float val = d + bias[row];
            out[row] = val;
            if (val > m) { s = s * expf(m - val) + 1.f; m = val; }
            else         { s += expf(val - m); }
        }
    }
    if (lane == 0) { smx[wid] = m; ssm[wid] = s; }
    __syncthreads();
    if (threadIdx.x == 0) {
        float M = smx[0], S = ssm[0];
#pragma unroll
        for (int i = 1; i < 4; ++i) {
            float mi = smx[i], si = ssm[i];
            if (mi > M) { S = S * expf(M - mi) + si; M = mi; }
            else        { S += si * expf(mi - M); }
        }
        pairs[b] = make_float2(M, S);
    }
}

// Every block deterministically reduces the 2048 (m,s) pairs to logC,
// then subtracts over its grid-stride slice of the logits.
__global__ __launch_bounds__(NTHR) void logsm_final(
    float* __restrict__ out, const float2* __restrict__ pairs) {
    __shared__ float smx[4], ssm[4];
    __shared__ float lc;
    float m = -INFINITY, s = 0.f;
    for (int i = threadIdx.x; i < NBLK; i += NTHR) {
        float2 p = pairs[i];
        if (p.x > m) { s = s * expf(m - p.x) + p.y; m = p.x; }
        else         { s += p.y * expf(p.x - m); }
    }
#pragma unroll
    for (int off = 32; off > 0; off >>= 1) {
        float mo = __shfl_down(m, off, 64);
        float so = __shfl_down(s, off, 64);
        if (mo > m) { s = s * expf(m - mo) + so; m = mo; }
        else        { s += so * expf(mo - m); }
    }
    const int wid = threadIdx.x >> 6, lane = threadIdx.x & 63;
    if (lane == 0) { smx[wid] = m; ssm[wid] = s; }
    __syncthreads();
    if (threadIdx.x == 0) {
        float M = smx[0], S = ssm[0];
#pragma unroll
        for (int i = 1; i < 4; ++i) {
            float mi = smx[i], si = ssm[i];
            if (mi > M) { S = S * expf(M - mi) + si; M = mi; }
            else        { S += si * expf(mi - M); }
        }
        lc = M + logf(S);
    }
    __syncthreads();
    float logC = lc;
    for (int i = blockIdx.x * NTHR + threadIdx.x; i < ODIM; i += gridDim.x * NTHR)
        out[i] -= logC;
}

// ---------- launch ----------

extern "C" void kernel_launch(void* const* d_in, const int* in_sizes, int n_in,
                              void* d_out, int out_size, void* d_ws, size_t ws_size,
                              hipStream_t stream) {
    const float* x     = (const float*)d_in[0];
    const float* h0    = (const float*)d_in[1];
    const float* w_ih1 = (const float*)d_in[2];
    const float* w_hh1 = (const float*)d_in[3];
    const float* b_ih1 = (const float*)d_in[4];
    const float* b_hh1 = (const float*)d_in[5];
    const float* w_ih2 = (const float*)d_in[6];
    const float* w_hh2 = (const float*)d_in[7];
    const float* b_ih2 = (const float*)d_in[8];
    const float* b_hh2 = (const float*)d_in[9];
    const float* w_out = (const float*)d_in[10];
    const float* b_out = (const float*)d_in[11];

    float* out    = (float*)d_out;        // log_softmax [50257]
    float* h2_out = out + ODIM;           // h2 [4096]

    float* ws   = (float*)d_ws;
    float* gi1  = ws;                     // 12288
    float* gh1  = ws + 12288;             // 12288
    float* gi2  = ws + 24576;             // 12288
    float* gh2  = ws + 36864;             // 12288
    float* h1   = ws + 49152;             // 4096
    float* act  = ws + 53248;             // 4096
    float2* pairs = (float2*)(ws + 57344);// 2048 float2

    gemv_dual<<<NBLK, NTHR, 0, stream>>>(w_ih1, x, b_ih1, gi1,
                                         w_hh1, h0, b_hh1, gh1);
    gru_gate<<<HDIM / NTHR, NTHR, 0, stream>>>(gi1, gh1, h0, h1, nullptr);

    gemv_dual<<<NBLK, NTHR, 0, stream>>>(w_ih2, h1, b_ih2, gi2,
                                         w_hh2, h1, b_hh2, gh2);
    gru_gate<<<HDIM / NTHR, NTHR, 0, stream>>>(gi2, gh2, h1, h2_out, act);

    gemv_logits_lse<<<NBLK, NTHR, 0, stream>>>(w_out, act, b_out, out, pairs);
    logsm_final<<<64, NTHR, 0, stream>>>(out, pairs);
}